// Round 4
// baseline (582.244 us; speedup 1.0000x reference)
//
#include <hip/hip_runtime.h>

// LIF neuron group: T=1000 sequential steps, N=65536 independent neurons.
// Memory-bound streaming: 524 MB read + 262 MB write per call.
// One thread per neuron; V / V_th state in registers; time axis chunked
// with a double-buffered prefetch (U=8) so ~16 loads/thread stay in flight.

#define T_STEPS   1000
#define NN        65536
#define UNROLL    8

__global__ __launch_bounds__(256) void lif_kernel(
    const float* __restrict__ inp,   // (T, N) input_current
    const float* __restrict__ noi,   // (T, N) noise
    float* __restrict__ out)         // (T, N) spikes
{
    const int n = blockIdx.x * blockDim.x + threadIdx.x;  // neuron id

    const float decay   = 0.05f;   // DT/TAU = 1/20
    const float nstd    = 0.1f;    // NOISE_STD
    const float eta     = 0.1f;    // ETA
    const float min_th  = 0.5f;
    const float max_th  = 2.0f;

    float V   = 0.0f;   // V_RESET
    float Vth = 1.0f;   // V_TH0

    const float* pi = inp + n;
    const float* pn = noi + n;
    float*       po = out + n;

    float curI[UNROLL], curN[UNROLL];
    float nxtI[UNROLL], nxtN[UNROLL];

    // Preload chunk 0
#pragma unroll
    for (int u = 0; u < UNROLL; ++u) {
        curI[u] = pi[u * NN];
        curN[u] = pn[u * NN];
    }
    pi += UNROLL * NN;
    pn += UNROLL * NN;

    const int NCHUNK = T_STEPS / UNROLL;  // 125, exact

    for (int c = 0; c < NCHUNK; ++c) {
        // Prefetch next chunk (16 independent loads in flight while we compute)
        if (c + 1 < NCHUNK) {
#pragma unroll
            for (int u = 0; u < UNROLL; ++u) {
                nxtI[u] = pi[u * NN];
                nxtN[u] = pn[u * NN];
            }
            pi += UNROLL * NN;
            pn += UNROLL * NN;
        }

        // Compute current chunk (register-resident state recurrence)
#pragma unroll
        for (int u = 0; u < UNROLL; ++u) {
            float Ieff = fmaf(nstd, curN[u], curI[u]);     // I + 0.1*noise
            V = fmaf(decay, Ieff - V, V);                  // V += decay*(Ieff - V)
            float spike = (V >= Vth) ? 1.0f : 0.0f;
            V = (spike > 0.0f) ? 0.0f : V;                 // reset on spike
            Vth = fminf(fmaxf(fmaf(eta, spike, Vth), min_th), max_th);
            po[u * NN] = spike;
        }
        po += UNROLL * NN;

        // Rotate buffers (register moves, fully unrolled)
#pragma unroll
        for (int u = 0; u < UNROLL; ++u) {
            curI[u] = nxtI[u];
            curN[u] = nxtN[u];
        }
    }
}

extern "C" void kernel_launch(void* const* d_in, const int* in_sizes, int n_in,
                              void* d_out, int out_size, void* d_ws, size_t ws_size,
                              hipStream_t stream) {
    const float* input_current = (const float*)d_in[0];
    const float* noise         = (const float*)d_in[1];
    float*       spikes        = (float*)d_out;

    dim3 grid(NN / 256);   // 256 blocks -> all 256 CUs active, 4 waves/CU
    dim3 block(256);
    lif_kernel<<<grid, block, 0, stream>>>(input_current, noise, spikes);
}

// Round 5
// 568.693 us; speedup vs baseline: 1.0238x; 1.0238x over previous
//
#include <hip/hip_runtime.h>

// LIF neuron group: T=1000 sequential steps, N=65536 independent neurons.
// 1 thread/neuron => 1024 waves = 1 wave/SIMD (occupancy is problem-capped),
// so ALL latency hiding must come from in-flight loads (ILP).
// Round 4 showed 201us latency-bound (~16 loads in flight, 900+cy exposed).
// This version: prefetch distance 2 (ping-pong A/B, outer loop unrolled x2)
// => ~32 loads/thread in flight, each buffer gets an extra compute phase of
// slack before its wait. All register arrays statically indexed.

#define T_STEPS   1000
#define NN        65536
#define U         8
#define NCHUNK    (T_STEPS / U)   // 125

__global__ __launch_bounds__(256) void lif_kernel(
    const float* __restrict__ inp,   // (T, N) input_current
    const float* __restrict__ noi,   // (T, N) noise
    float* __restrict__ out)         // (T, N) spikes
{
    const int n = blockIdx.x * blockDim.x + threadIdx.x;  // neuron id

    const float decay  = 0.05f;   // DT/TAU
    const float nstd   = 0.1f;    // NOISE_STD
    const float eta    = 0.1f;    // ETA
    const float min_th = 0.5f;
    const float max_th = 2.0f;

    float V   = 0.0f;   // V_RESET
    float Vth = 1.0f;   // V_TH0

    const float* pi = inp + n;
    const float* pn = noi + n;
    float*       po = out + n;

    float aI[U], aN[U], bI[U], bN[U];

    // Preload chunk 0 -> A, chunk 1 -> B  (32 loads in flight immediately)
#pragma unroll
    for (int u = 0; u < U; ++u) { aI[u] = pi[u * NN]; aN[u] = pn[u * NN]; }
    pi += U * NN; pn += U * NN;
#pragma unroll
    for (int u = 0; u < U; ++u) { bI[u] = pi[u * NN]; bN[u] = pn[u * NN]; }
    pi += U * NN; pn += U * NN;

#define LIF_COMPUTE(bufI, bufN)                                         \
    _Pragma("unroll")                                                   \
    for (int u = 0; u < U; ++u) {                                       \
        float Ieff = fmaf(nstd, bufN[u], bufI[u]);                      \
        V = fmaf(decay, Ieff - V, V);                                   \
        float spike = (V >= Vth) ? 1.0f : 0.0f;                         \
        V = (spike > 0.0f) ? 0.0f : V;                                  \
        Vth = fminf(fmaxf(fmaf(eta, spike, Vth), min_th), max_th);      \
        po[u * NN] = spike;                                             \
    }                                                                   \
    po += U * NN;

#define LIF_PREFETCH(bufI, bufN)                                        \
    _Pragma("unroll")                                                   \
    for (int u = 0; u < U; ++u) { bufI[u] = pi[u * NN];                 \
                                  bufN[u] = pn[u * NN]; }               \
    pi += U * NN; pn += U * NN;

    // Pairs cover chunks 0..123; chunk 124 is the epilogue (sits in A).
    for (int c = 0; c < NCHUNK - 1; c += 2) {      // c = 0,2,...,122
        LIF_COMPUTE(aI, aN);                       // chunk c   (waits A)
        LIF_PREFETCH(aI, aN);                      // chunk c+2 (<=124, always valid)
        LIF_COMPUTE(bI, bN);                       // chunk c+1 (waits B)
        if (c + 3 < NCHUNK) { LIF_PREFETCH(bI, bN); }  // chunk c+3 (skip at c=122)
    }
    LIF_COMPUTE(aI, aN);                           // chunk 124

#undef LIF_COMPUTE
#undef LIF_PREFETCH
}

extern "C" void kernel_launch(void* const* d_in, const int* in_sizes, int n_in,
                              void* d_out, int out_size, void* d_ws, size_t ws_size,
                              hipStream_t stream) {
    const float* input_current = (const float*)d_in[0];
    const float* noise         = (const float*)d_in[1];
    float*       spikes        = (float*)d_out;

    dim3 grid(NN / 256);   // 256 blocks -> all 256 CUs, 4 waves/CU (problem-capped)
    dim3 block(256);
    lif_kernel<<<grid, block, 0, stream>>>(input_current, noise, spikes);
}